// Round 1
// baseline (1358.811 us; speedup 1.0000x reference)
//
#include <hip/hip_runtime.h>

#define D_FEAT 64
#define N_NODES 100000

// SpMM: out[r] = sum_{e: rows[e]==r} vals[e] * embeds[cols[e]]
// Baseline: atomic scatter. 16 threads per edge, float4 per thread.
__global__ void spmm_atomic_kernel(const int* __restrict__ rows,
                                   const int* __restrict__ cols,
                                   const float* __restrict__ vals,
                                   const float* __restrict__ embeds,
                                   float* __restrict__ out,
                                   int n_edges) {
    long long t = (long long)blockIdx.x * blockDim.x + threadIdx.x;
    int e  = (int)(t >> 4);        // 16 threads per edge
    int f4 = ((int)t & 15) * 4;    // feature offset (float4 granularity)
    if (e >= n_edges) return;

    int   r = rows[e];
    int   c = cols[e];
    float v = vals[e];

    const float4 emb = *reinterpret_cast<const float4*>(&embeds[(long long)c * D_FEAT + f4]);
    float* o = &out[(long long)r * D_FEAT + f4];
    atomicAdd(o + 0, v * emb.x);
    atomicAdd(o + 1, v * emb.y);
    atomicAdd(o + 2, v * emb.z);
    atomicAdd(o + 3, v * emb.w);
}

extern "C" void kernel_launch(void* const* d_in, const int* in_sizes, int n_in,
                              void* d_out, int out_size, void* d_ws, size_t ws_size,
                              hipStream_t stream) {
    const int*   rows   = (const int*)d_in[0];
    const int*   cols   = (const int*)d_in[1];
    const float* vals   = (const float*)d_in[2];
    const float* embeds = (const float*)d_in[3];
    float*       out    = (float*)d_out;

    int n_edges = in_sizes[0];

    // Output must be zeroed every call (harness poisons once, never restores).
    hipMemsetAsync(d_out, 0, (size_t)out_size * sizeof(float), stream);

    long long total_threads = (long long)n_edges * 16;
    int block = 256;
    long long grid = (total_threads + block - 1) / block;
    spmm_atomic_kernel<<<(int)grid, block, 0, stream>>>(rows, cols, vals, embeds, out, n_edges);
}

// Round 2
// 305.194 us; speedup vs baseline: 4.4523x; 4.4523x over previous
//
#include <hip/hip_runtime.h>

#define D_FEAT 64
#define NN 100000
#define CHUNK 1024
#define SCAN_THREADS 256   // 4 elements per thread -> 1024-elem chunks

// ---------------- Phase A: histogram of rows ----------------
__global__ void hist_kernel(const int* __restrict__ rows, int* __restrict__ counts, int E) {
    int i = blockIdx.x * blockDim.x + threadIdx.x;
    int stride = gridDim.x * blockDim.x;
    for (; i < E; i += stride) atomicAdd(&counts[rows[i]], 1);
}

// ---------------- Phase B: exclusive scan over NN counts ----------------
__global__ void scan1_kernel(const int* __restrict__ counts, int* __restrict__ blockSums, int n) {
    __shared__ int lds[SCAN_THREADS];
    int b = blockIdx.x, t = threadIdx.x;
    int base = b * CHUNK;
    int s = 0;
    #pragma unroll
    for (int k = 0; k < 4; k++) {
        int idx = base + t * 4 + k;
        if (idx < n) s += counts[idx];
    }
    lds[t] = s; __syncthreads();
    for (int off = SCAN_THREADS / 2; off > 0; off >>= 1) {
        if (t < off) lds[t] += lds[t + off];
        __syncthreads();
    }
    if (t == 0) blockSums[b] = lds[0];
}

__global__ void scan2_kernel(int* __restrict__ blockSums, int nb, int* __restrict__ offsets, int E) {
    if (blockIdx.x == 0 && threadIdx.x == 0) {
        int run = 0;
        for (int i = 0; i < nb; i++) { int v = blockSums[i]; blockSums[i] = run; run += v; }
        offsets[NN] = E;
    }
}

__global__ void scan3_kernel(const int* __restrict__ counts, const int* __restrict__ blockSums,
                             int* __restrict__ offsets, int n) {
    __shared__ int lds[SCAN_THREADS];
    int b = blockIdx.x, t = threadIdx.x;
    int base = b * CHUNK;
    int v[4]; int s = 0;
    #pragma unroll
    for (int k = 0; k < 4; k++) {
        int idx = base + t * 4 + k;
        v[k] = (idx < n) ? counts[idx] : 0;
        s += v[k];
    }
    lds[t] = s; __syncthreads();
    // Hillis-Steele inclusive scan over thread sums
    for (int off = 1; off < SCAN_THREADS; off <<= 1) {
        int x = (t >= off) ? lds[t - off] : 0;
        __syncthreads();
        lds[t] += x;
        __syncthreads();
    }
    int excl = (t > 0) ? lds[t - 1] : 0;
    excl += blockSums[b];
    #pragma unroll
    for (int k = 0; k < 4; k++) {
        int idx = base + t * 4 + k;
        if (idx < n) { offsets[idx] = excl; excl += v[k]; }
    }
}

// ---------------- Phase C: scatter edges into CSR order ----------------
__global__ void scatter_kernel(const int* __restrict__ rows, const int* __restrict__ cols,
                               const float* __restrict__ vals,
                               const int* __restrict__ offsets, int* __restrict__ cursors,
                               int2* __restrict__ sedges, int E) {
    int i = blockIdx.x * blockDim.x + threadIdx.x;
    int stride = gridDim.x * blockDim.x;
    for (; i < E; i += stride) {
        int r = rows[i];
        int pos = offsets[r] + atomicAdd(&cursors[r], 1);
        sedges[pos] = make_int2(cols[i], __float_as_int(vals[i]));
    }
}

// ---------------- Phase D: segmented SpMM, one wave per row ----------------
__global__ void spmm_csr_kernel(const int* __restrict__ offsets, const int2* __restrict__ sedges,
                                const float* __restrict__ embeds, float* __restrict__ out) {
    int wave = (blockIdx.x * blockDim.x + threadIdx.x) >> 6;
    int lane = threadIdx.x & 63;
    if (wave >= NN) return;
    int s = offsets[wave], e = offsets[wave + 1];
    float acc = 0.f;
    for (int base = s; base < e; base += 64) {
        int idx = base + lane;
        int c = 0; float v = 0.f;
        if (idx < e) {
            int2 se = sedges[idx];
            c = se.x; v = __int_as_float(se.y);
        }
        int m = min(64, e - base);
        for (int j = 0; j < m; j++) {
            int   cj = __shfl(c, j);
            float vj = __shfl(v, j);
            acc += vj * embeds[(long long)cj * D_FEAT + lane];
        }
    }
    out[(long long)wave * D_FEAT + lane] = acc;
}

// ---------------- fallback: baseline atomic scatter ----------------
__global__ void spmm_atomic_kernel(const int* __restrict__ rows, const int* __restrict__ cols,
                                   const float* __restrict__ vals, const float* __restrict__ embeds,
                                   float* __restrict__ out, int n_edges) {
    long long t = (long long)blockIdx.x * blockDim.x + threadIdx.x;
    int e = (int)(t >> 4);
    int f4 = ((int)t & 15) * 4;
    if (e >= n_edges) return;
    int r = rows[e], c = cols[e];
    float v = vals[e];
    const float4 emb = *reinterpret_cast<const float4*>(&embeds[(long long)c * D_FEAT + f4]);
    float* o = &out[(long long)r * D_FEAT + f4];
    atomicAdd(o + 0, v * emb.x);
    atomicAdd(o + 1, v * emb.y);
    atomicAdd(o + 2, v * emb.z);
    atomicAdd(o + 3, v * emb.w);
}

extern "C" void kernel_launch(void* const* d_in, const int* in_sizes, int n_in,
                              void* d_out, int out_size, void* d_ws, size_t ws_size,
                              hipStream_t stream) {
    const int*   rows   = (const int*)d_in[0];
    const int*   cols   = (const int*)d_in[1];
    const float* vals   = (const float*)d_in[2];
    const float* embeds = (const float*)d_in[3];
    float*       out    = (float*)d_out;
    int E = in_sizes[0];

    int NB = (NN + CHUNK - 1) / CHUNK;

    // Workspace layout (8B-aligned first):
    //   sedges  : E int2            (8E bytes)
    //   offsets : NN+1 ints
    //   cursors : NN ints
    //   bsums   : NB ints
    size_t need = (size_t)E * 8 + ((size_t)NN + 1 + NN + NB) * 4;
    if (ws_size < need) {
        // fallback: atomic baseline
        hipMemsetAsync(d_out, 0, (size_t)out_size * sizeof(float), stream);
        long long total = (long long)E * 16;
        int block = 256;
        spmm_atomic_kernel<<<(int)((total + block - 1) / block), block, 0, stream>>>(
            rows, cols, vals, embeds, out, E);
        return;
    }

    char* ws = (char*)d_ws;
    int2* sedges  = (int2*)ws;                       ws += (size_t)E * 8;
    int*  offsets = (int*)ws;                        ws += ((size_t)NN + 1) * 4;
    int*  cursors = (int*)ws;                        ws += (size_t)NN * 4;
    int*  bsums   = (int*)ws;

    // A: histogram (counts live in `cursors`)
    hipMemsetAsync(cursors, 0, (size_t)NN * 4, stream);
    hist_kernel<<<2048, 256, 0, stream>>>(rows, cursors, E);

    // B: exclusive scan counts -> offsets
    scan1_kernel<<<NB, SCAN_THREADS, 0, stream>>>(cursors, bsums, NN);
    scan2_kernel<<<1, 64, 0, stream>>>(bsums, NB, offsets, E);
    scan3_kernel<<<NB, SCAN_THREADS, 0, stream>>>(cursors, bsums, offsets, NN);

    // C: scatter into CSR
    hipMemsetAsync(cursors, 0, (size_t)NN * 4, stream);
    scatter_kernel<<<2048, 256, 0, stream>>>(rows, cols, vals, offsets, cursors, sedges, E);

    // D: segmented SpMM, one wave (64 lanes = 64 features) per row
    int waves_per_block = 256 / 64;
    int blocks = (NN + waves_per_block - 1) / waves_per_block;
    spmm_csr_kernel<<<blocks, 256, 0, stream>>>(offsets, sedges, embeds, out);
}